// Round 3
// baseline (52.319 us; speedup 1.0000x reference)
//
#include <hip/hip_runtime.h>

// Problem: B=8, C=128, H=W=256, V=32.
// out[b][c][v] = max over pixels p of encoded[b][c][p] where masks[b][p] == v+1.
// encoded: (B,C,H,W) f32; masks: (B,1,H,W) int32 in [1,32]; out: (B,C,V,1) f32.
//
// Memory-bound: 268 MB encoded streamed once from HBM. Masks (2 MB) are
// re-read once per channel (268 MB of L1/L2 traffic) and must stay
// L2-resident -> encoded is loaded NON-TEMPORAL (nt flag) so it doesn't
// evict them. Roofline ~43us at 6.3 TB/s.

#define NSEG 32
#define TPB  256
#define PIX  65536       // H*W
#define PIX4 (PIX/4)     // float4s per (b,c)
#define NEG_INF_KEY 0x007FFFFFu   // monotone key of -inf

// native vector types for nontemporal builtins (HIP_vector_type rejected)
typedef float __attribute__((ext_vector_type(4))) f32x4;

// monotone map: float bits -> unsigned key preserving < ordering
__device__ __forceinline__ unsigned fkey(float f) {
    unsigned u = __float_as_uint(f);
    return u ^ (unsigned)(((int)u >> 31) | 0x80000000);
}

__global__ __launch_bounds__(TPB, 4) void VectorsFromMaskV2_kernel(
    const f32x4* __restrict__ enc,
    const int4*  __restrict__ masks,
    float* __restrict__ out)
{
    // per-thread private 32-slot max arrays, stride 33 to spread banks:
    // bank = (tid*33 + slot) % 32 = (tid + slot) % 32
    __shared__ unsigned lmax[TPB * 33];   // 33792 B
    __shared__ unsigned part[8 * NSEG];   //  1024 B

    const int tid = threadIdx.x;
    const int bc  = blockIdx.x;           // b*128 + c
    const int b   = bc >> 7;

    #pragma unroll
    for (int i = tid; i < TPB * 33; i += TPB) lmax[i] = NEG_INF_KEY;
    __syncthreads();

    const f32x4* __restrict__ ep = enc   + (size_t)bc * PIX4;
    const int4*  __restrict__ mp = masks + (size_t)b  * PIX4;
    const int base = tid * 33 - 1;        // id in [1..32] -> slot base+id

    #pragma unroll 4
    for (int it = 0; it < PIX4 / TPB; ++it) {
        const int i = it * TPB + tid;     // coalesced: lane i reads float4 i
        f32x4 e = __builtin_nontemporal_load(&ep[i]);   // nt: don't evict masks
        int4  m = mp[i];                                // cached: L2-resident
        atomicMax(&lmax[base + m.x], fkey(e.x));   // ds_max_u32, no rtn
        atomicMax(&lmax[base + m.y], fkey(e.y));
        atomicMax(&lmax[base + m.z], fkey(e.z));
        atomicMax(&lmax[base + m.w], fkey(e.w));
    }
    __syncthreads();

    // stage 1: 8 groups of 32 threads; group g reduces source threads
    // [g*32, g*32+32) for segment v = tid&31. bank = (i + v) % 32 -> 2-way max.
    const int v = tid & 31, g = tid >> 5;
    unsigned k = NEG_INF_KEY;
    for (int i = 0; i < 32; ++i) {
        unsigned t = lmax[(g * 32 + i) * 33 + v];
        k = (t > k) ? t : k;
    }
    part[(g << 5) | v] = k;
    __syncthreads();

    // stage 2: 32 threads fold the 8 group partials, unmap key, write out
    if (tid < NSEG) {
        unsigned kk = part[tid];
        #pragma unroll
        for (int g2 = 1; g2 < 8; ++g2) {
            unsigned t = part[(g2 << 5) | tid];
            kk = (t > kk) ? t : kk;
        }
        unsigned m2 = (kk & 0x80000000u) ? 0x80000000u : 0xFFFFFFFFu;
        __builtin_nontemporal_store(__uint_as_float(kk ^ m2), &out[bc * NSEG + tid]);
    }
}

extern "C" void kernel_launch(void* const* d_in, const int* in_sizes, int n_in,
                              void* d_out, int out_size, void* d_ws, size_t ws_size,
                              hipStream_t stream) {
    const f32x4* enc   = (const f32x4*)d_in[0];
    const int4*  masks = (const int4*)d_in[1];
    float* out = (float*)d_out;
    // grid: one block per (b, c) pair = 8*128 = 1024 blocks
    VectorsFromMaskV2_kernel<<<1024, TPB, 0, stream>>>(enc, masks, out);
}

// Round 4
// 46.744 us; speedup vs baseline: 1.1193x; 1.1193x over previous
//
#include <hip/hip_runtime.h>

// Problem: B=8, C=128, H=W=256, V=32.
// out[b][c][v] = max over pixels p of encoded[b][c][p] where masks[b][p] == v+1.
// encoded: (B,C,H,W) f32; masks: (B,1,H,W) int32 in [1,32]; out: (B,C,V,1) f32.
//
// Memory-bound: 268 MB encoded streamed once from HBM; ~43us at 6.3 TB/s.
// Masks (2 MB per batch) are re-read once per channel (268 MB of cache
// traffic). XCD-aware block swizzle maps all 128 channel-blocks of batch b
// to XCD b, so each XCD's mask set (2 MB) stays resident in its 4 MB L2
// instead of 8 batches (16 MB) thrashing every XCD's L2.
// NOTE: nontemporal loads on encoded were tried and HURT (-12%) -- gfx950
// nt streaming reads lose L2 merge benefits. Keep regular loads.

#define NSEG 32
#define TPB  256
#define PIX  65536       // H*W
#define PIX4 (PIX/4)     // float4s per (b,c)
#define NEG_INF_KEY 0x007FFFFFu   // monotone key of -inf

// monotone map: float bits -> unsigned key preserving < ordering
__device__ __forceinline__ unsigned fkey(float f) {
    unsigned u = __float_as_uint(f);
    return u ^ (unsigned)(((int)u >> 31) | 0x80000000);
}

__global__ __launch_bounds__(TPB, 4) void VectorsFromMaskV2_kernel(
    const float4* __restrict__ enc,
    const int4*  __restrict__ masks,
    float* __restrict__ out)
{
    // per-thread private 32-slot max arrays, stride 33 to spread banks:
    // bank = (tid*33 + slot) % 32 = (tid + slot) % 32
    __shared__ unsigned lmax[TPB * 33];   // 33792 B
    __shared__ unsigned part[8 * NSEG];   //  1024 B

    const int tid = threadIdx.x;
    // XCD swizzle: hardware round-robins blockIdx across 8 XCDs, so
    // bc = (i%8)*128 + i/8 gives XCD x all 128 channels of batch x.
    // Bijective: 1024 % 8 == 0.
    const int bc  = (blockIdx.x & 7) * 128 + (blockIdx.x >> 3);
    const int b   = bc >> 7;

    #pragma unroll
    for (int i = tid; i < TPB * 33; i += TPB) lmax[i] = NEG_INF_KEY;
    __syncthreads();

    const float4* __restrict__ ep = enc   + (size_t)bc * PIX4;
    const int4*  __restrict__ mp = masks + (size_t)b  * PIX4;
    const int base = tid * 33 - 1;        // id in [1..32] -> slot base+id

    #pragma unroll 4
    for (int it = 0; it < PIX4 / TPB; ++it) {
        const int i = it * TPB + tid;     // coalesced: lane i reads float4 i
        float4 e = ep[i];
        int4   m = mp[i];                 // L2-resident on this XCD
        atomicMax(&lmax[base + m.x], fkey(e.x));   // ds_max_u32, no rtn
        atomicMax(&lmax[base + m.y], fkey(e.y));
        atomicMax(&lmax[base + m.z], fkey(e.z));
        atomicMax(&lmax[base + m.w], fkey(e.w));
    }
    __syncthreads();

    // stage 1: 8 groups of 32 threads; group g reduces source threads
    // [g*32, g*32+32) for segment v = tid&31. bank = (i + v) % 32 -> 2-way max.
    const int v = tid & 31, g = tid >> 5;
    unsigned k = NEG_INF_KEY;
    for (int i = 0; i < 32; ++i) {
        unsigned t = lmax[(g * 32 + i) * 33 + v];
        k = (t > k) ? t : k;
    }
    part[(g << 5) | v] = k;
    __syncthreads();

    // stage 2: 32 threads fold the 8 group partials, unmap key, write out
    if (tid < NSEG) {
        unsigned kk = part[tid];
        #pragma unroll
        for (int g2 = 1; g2 < 8; ++g2) {
            unsigned t = part[(g2 << 5) | tid];
            kk = (t > kk) ? t : kk;
        }
        unsigned m2 = (kk & 0x80000000u) ? 0x80000000u : 0xFFFFFFFFu;
        out[bc * NSEG + tid] = __uint_as_float(kk ^ m2);
    }
}

extern "C" void kernel_launch(void* const* d_in, const int* in_sizes, int n_in,
                              void* d_out, int out_size, void* d_ws, size_t ws_size,
                              hipStream_t stream) {
    const float4* enc   = (const float4*)d_in[0];
    const int4*   masks = (const int4*)d_in[1];
    float* out = (float*)d_out;
    // grid: one block per (b, c) pair = 8*128 = 1024 blocks
    VectorsFromMaskV2_kernel<<<1024, TPB, 0, stream>>>(enc, masks, out);
}